// Round 7
// baseline (12.127 us; speedup 1.0000x reference)
//
#include <hip/hip_runtime.h>
#include <hip/hip_bf16.h>

#define BATCH 1024
#define INF   512
#define OUTF  512
#define BM    32            // batch tile
#define BN    32            // out-feature tile
#define NQ    (INF / 8)     // 64 quads (8 bf16 = 16B) per row
#define KT    32            // AEG tail length (contrib beyond < 1e-30)
#define K0    (INF - KT)    // 480, even -> (i+k) parity preserved

typedef __attribute__((ext_vector_type(8))) short s16x8;   // 8 bf16
typedef __attribute__((ext_vector_type(4))) float f32x4;   // MFMA acc

__device__ __forceinline__ unsigned int packbf2(float f0, float f1) {
  __hip_bfloat162 h2;
  h2.x = __float2bfloat16(f0);   // RNE
  h2.y = __float2bfloat16(f1);
  unsigned int u;
  __builtin_memcpy(&u, &h2, 4);
  return u;   // low16 = f0 (k-ascending)
}
__device__ __forceinline__ uint4 pack8(const float4& a, const float4& b) {
  uint4 q;
  q.x = packbf2(a.x, a.y); q.y = packbf2(a.z, a.w);
  q.z = packbf2(b.x, b.y); q.w = packbf2(b.z, b.w);
  return q;
}
__device__ __forceinline__ float bflo(unsigned int u) { return __uint_as_float(u << 16); }
__device__ __forceinline__ float bfhi(unsigned int u) { return __uint_as_float(u & 0xffff0000u); }

#define UNPACK8(Q, A)                                              \
  A[0] = bflo((Q).x); A[1] = bfhi((Q).x);                          \
  A[2] = bflo((Q).y); A[3] = bfhi((Q).y);                          \
  A[4] = bflo((Q).z); A[5] = bfhi((Q).z);                          \
  A[6] = bflo((Q).w); A[7] = bfhi((Q).w);

// Whole-K, single-barrier, 2-blocks/CU fused kernel (R6 geometry).
// R7: AEG tail reads bf16 straight from the GEMM tiles (x) / packed wt4 (w):
// tail LDS-read instrs halved, xt buffer + its staging eliminated.
__global__ __launch_bounds__(256) void semilinear_fused(
    const float* __restrict__ x,    // (1024,512)
    const float* __restrict__ w,    // (512,512)
    const float* __restrict__ pw,   // (512,512)
    const float* __restrict__ pb,   // (512,)
    float* __restrict__ out)        // (1024,512)
{
  // bf16 K-major tiles, quad = 16B = 8 k's, XOR-swizzled (T2/G4).
  __shared__ uint4 xs[BM][NQ];        // 32 KB  (also serves the x AEG tail)
  __shared__ uint4 ps[BN][NQ];        // 32 KB
  __shared__ uint4 wt4[BN][5];        // 2.5 KB: w tail bf16, quads 0..3 used
                                      // (row=20 words -> 8 bank-groups, 2-way)

  // ---- bijective XCD-aware remap (T1): hw XCD = blockIdx % 8 on MI355X ----
  const int id  = blockIdx.x;
  const int xcd = id & 7;
  const int c   = id >> 3;                  // 0..63
  const int bm  = (xcd * 4 + (c >> 4)) * BM;
  const int bn  = (c & 15) * BN;

  const int t    = threadIdx.x;
  const int lane = t & 63;
  const int wid  = t >> 6;            // 0..3
  const int rh   = wid >> 1;          // row-half
  const int ch   = wid & 1;           // col-half

  // ---- stage both GEMM tiles: thread t -> row t>>3, quads (t&7)+{0,8,..,56}
  {
    const int r  = t >> 3;            // 0..31
    const int q0 = t & 7;
    const float* xsrc = x  + (size_t)(bm + r) * INF;
    const float* psrc = pw + (size_t)(bn + r) * INF;
    #pragma unroll
    for (int j = 0; j < 8; ++j) {
      const int q = q0 + j * 8;       // lanes cover 256B/row contiguously
      float4 xv0 = *(const float4*)(xsrc + q * 8);
      float4 xv1 = *(const float4*)(xsrc + q * 8 + 4);
      float4 pv0 = *(const float4*)(psrc + q * 8);
      float4 pv1 = *(const float4*)(psrc + q * 8 + 4);
      xs[r][q ^ (r & 7)] = pack8(xv0, xv1);
      ps[r][q ^ (r & 7)] = pack8(pv0, pv1);
    }
  }
  // ---- stage bf16 w-tail (128 threads, one ds_write each) ----
  if (t < 128) {
    const int r  = t >> 2;            // 0..31
    const int kq = t & 3;             // 0..3
    const float* src = w + (size_t)(bn + r) * INF + K0 + kq * 8;
    float4 v0 = *(const float4*)(src);
    float4 v1 = *(const float4*)(src + 4);
    wt4[r][kq] = pack8(v0, v1);
  }
  __syncthreads();   // the ONLY barrier

  // ---- GEMM: 16 back-to-back MFMAs (compiler pipelines the 32 ds_reads) ----
  f32x4 acc = {0.f, 0.f, 0.f, 0.f};
  const int ar = rh * 16 + (lane & 15);   // A row (batch)
  const int br = ch * 16 + (lane & 15);   // B row (out col)
  const int kh = lane >> 4;               // k-quad within K=32 step
  #pragma unroll
  for (int ks = 0; ks < INF / 32; ++ks) {
    const int q = ks * 4 + kh;
    uint4 av = xs[ar][q ^ (ar & 7)];
    uint4 bv = ps[br][q ^ (br & 7)];
    s16x8 af, bf;
    __builtin_memcpy(&af, &av, 16);
    __builtin_memcpy(&bf, &bv, 16);
    acc = __builtin_amdgcn_mfma_f32_16x16x32_bf16(af, bf, acc, 0, 0, 0);
  }

  // ---- AEG tail on the accumulator tile, operands bf16 from LDS ----
  // C/D layout (R3-R6 validated): col = lane&15, row = (lane>>4)*4 + reg
  const int lrow = rh * 16 + (lane >> 4) * 4;
  const int lcol = ch * 16 + (lane & 15);
  const int ocol = bn + lcol;

  float rr0 = 0.f, rr1 = 0.f, rr2 = 0.f, rr3 = 0.f;
  const bool ev = ((lcol & 1) == 0);      // parity of i (bn is even)

  // r = r*m + w*x ; m = x if ((i+k) even) else w ; k parity == u parity
#define AEGSTEP(WK, XV, KEV, RR)                                            \
  { const float p = (WK) * (XV);                                            \
    const float m = (KEV) ? (ev ? (XV) : (WK)) : (ev ? (WK) : (XV));        \
    RR = fmaf(RR, m, p); }

  #pragma unroll
  for (int kq = 0; kq < 4; ++kq) {        // k = K0 + kq*8 + u
    uint4 wv4 = wt4[lcol][kq];
    float wk[8];
    UNPACK8(wv4, wk);
    float xk0[8], xk1[8], xk2[8], xk3[8];
    { const int r = lrow + 0; uint4 q = xs[r][(60 + kq) ^ (r & 7)]; UNPACK8(q, xk0); }
    { const int r = lrow + 1; uint4 q = xs[r][(60 + kq) ^ (r & 7)]; UNPACK8(q, xk1); }
    { const int r = lrow + 2; uint4 q = xs[r][(60 + kq) ^ (r & 7)]; UNPACK8(q, xk2); }
    { const int r = lrow + 3; uint4 q = xs[r][(60 + kq) ^ (r & 7)]; UNPACK8(q, xk3); }
    #pragma unroll
    for (int u = 0; u < 8; ++u) {
      const bool kev = ((u & 1) == 0);    // K0 even -> k parity == u parity
      AEGSTEP(wk[u], xk0[u], kev, rr0);
      AEGSTEP(wk[u], xk1[u], kev, rr1);
      AEGSTEP(wk[u], xk2[u], kev, rr2);
      AEGSTEP(wk[u], xk3[u], kev, rr3);
    }
  }
#undef AEGSTEP

  // ---- epilogue: sigmoid(aeg) * (proj + bias) ----
  const float pbv = pb[ocol];
  out[(size_t)(bm + lrow + 0) * OUTF + ocol] = (acc[0] + pbv) / (1.f + __expf(-rr0));
  out[(size_t)(bm + lrow + 1) * OUTF + ocol] = (acc[1] + pbv) / (1.f + __expf(-rr1));
  out[(size_t)(bm + lrow + 2) * OUTF + ocol] = (acc[2] + pbv) / (1.f + __expf(-rr2));
  out[(size_t)(bm + lrow + 3) * OUTF + ocol] = (acc[3] + pbv) / (1.f + __expf(-rr3));
}

extern "C" void kernel_launch(void* const* d_in, const int* in_sizes, int n_in,
                              void* d_out, int out_size, void* d_ws, size_t ws_size,
                              hipStream_t stream) {
  const float* x  = (const float*)d_in[0];
  const float* w  = (const float*)d_in[1];   // (1,512,512) flat
  const float* pw = (const float*)d_in[2];
  const float* pb = (const float*)d_in[3];
  float* out = (float*)d_out;

  semilinear_fused<<<dim3(512), dim3(256), 0, stream>>>(x, w, pw, pb, out);
}

// Round 8
// 10.846 us; speedup vs baseline: 1.1182x; 1.1182x over previous
//
#include <hip/hip_runtime.h>
#include <hip/hip_bf16.h>

#define BATCH 1024
#define INF   512
#define OUTF  512
#define BM    32            // batch tile
#define BN    64            // out-feature tile
#define NQ    (INF / 8)     // 64 quads (8 bf16 = 16B) per row
#define KT    32            // AEG tail length (contrib beyond < 1e-30)
#define K0    (INF - KT)    // 480, even -> (i+k) parity preserved

typedef __attribute__((ext_vector_type(8))) short s16x8;   // 8 bf16
typedef __attribute__((ext_vector_type(4))) float f32x4;   // MFMA acc

__device__ __forceinline__ unsigned int packbf2(float f0, float f1) {
  __hip_bfloat162 h2;
  h2.x = __float2bfloat16(f0);   // RNE
  h2.y = __float2bfloat16(f1);
  unsigned int u;
  __builtin_memcpy(&u, &h2, 4);
  return u;   // low16 = f0 (k-ascending)
}
__device__ __forceinline__ uint4 pack8(const float4& a, const float4& b) {
  uint4 q;
  q.x = packbf2(a.x, a.y); q.y = packbf2(a.z, a.w);
  q.z = packbf2(b.x, b.y); q.w = packbf2(b.z, b.w);
  return q;
}

// Whole-K single-barrier fused kernel (R5 — best measured: 10.83 µs).
// 512 thr / 8 waves; wave w: row-half wr=w>>2 (16 of BM), col wc=w&3 (16 of BN).
// Grid 256 blocks = 1/CU, XCD-swizzled so each XCD owns 4 bm-rows x all 8 bn.
__global__ __launch_bounds__(512) void semilinear_fused(
    const float* __restrict__ x,    // (1024,512)
    const float* __restrict__ w,    // (512,512)
    const float* __restrict__ pw,   // (512,512)
    const float* __restrict__ pb,   // (512,)
    float* __restrict__ out)        // (1024,512)
{
  // bf16 K-major tiles, quad = 16B = 8 k's. XOR-swizzle quad^(row&7) (T2/G4):
  // frag reads (fixed quad, 16 rows) spread over 8 bank-groups -> 2-way, free.
  __shared__ uint4 xs[BM][NQ];                    // 32 KB
  __shared__ uint4 ps[BN][NQ];                    // 64 KB
  // fp32 AEG tails, padded to 36 (rows float4-aligned, reads <=2-way)
  __shared__ __align__(16) float wt[BN][KT + 4];  // 9 KB
  __shared__ __align__(16) float xt[BM][KT + 4];  // 4.5 KB

  // ---- bijective XCD-aware remap (T1): id%8 = XCD on MI355X ----
  const int id    = blockIdx.y * gridDim.x + blockIdx.x;  // 0..255
  const int xcd   = id & 7;
  const int chunk = id >> 3;            // 0..31
  const int bn    = (chunk & 7) * BN;   // 8 col-tiles per XCD
  const int bm    = (xcd * 4 + (chunk >> 3)) * BM;  // 4 row-tiles per XCD

  const int t    = threadIdx.x;
  const int lane = t & 63;
  const int wid  = t >> 6;              // 0..7
  const int wr   = wid >> 2;            // 0..1
  const int wc   = wid & 3;             // 0..3

  // ---- stage x tile: thread t -> row t>>4, quads (t&15)+{0,16,32,48} ----
  {
    const int r  = t >> 4;              // 0..31
    const int q0 = t & 15;
    const float* src = x + (size_t)(bm + r) * INF;
    #pragma unroll
    for (int j = 0; j < 4; ++j) {
      const int q = q0 + j * 16;        // lanes cover q contiguously (coalesced)
      float4 v0 = *(const float4*)(src + q * 8);
      float4 v1 = *(const float4*)(src + q * 8 + 4);
      xs[r][q ^ (r & 7)] = pack8(v0, v1);
    }
  }
  // ---- stage pw tile: thread t -> row t>>3, quads (t&7)+{0,8,...,56} ----
  {
    const int r  = t >> 3;              // 0..63
    const int q0 = t & 7;
    const float* src = pw + (size_t)(bn + r) * INF;
    #pragma unroll
    for (int j = 0; j < 8; ++j) {
      const int q = q0 + j * 8;
      float4 v0 = *(const float4*)(src + q * 8);
      float4 v1 = *(const float4*)(src + q * 8 + 4);
      ps[r][q ^ (r & 7)] = pack8(v0, v1);
    }
  }
  // ---- stage fp32 tails (one-time) ----
  {
    const int r  = t >> 3;              // 0..63
    const int c4 = (t & 7) * 4;         // 0..28
    *(float4*)&wt[r][c4] =
        *(const float4*)&w[(size_t)(bn + r) * INF + K0 + c4];
    if (t < 256) {
      const int r2 = t >> 3;            // 0..31
      *(float4*)&xt[r2][c4] =
          *(const float4*)&x[(size_t)(bm + r2) * INF + K0 + c4];
    }
  }
  __syncthreads();   // the ONLY barrier

  // ---- GEMM: 16 back-to-back MFMAs (compiler pipelines the 32 ds_reads) ----
  f32x4 acc = {0.f, 0.f, 0.f, 0.f};
  const int ar = wr * 16 + (lane & 15);   // A row (batch)
  const int br = wc * 16 + (lane & 15);   // B row (out col)
  const int kh = lane >> 4;               // k-quad within K=32 step
  #pragma unroll
  for (int ks = 0; ks < INF / 32; ++ks) {
    const int q = ks * 4 + kh;
    uint4 av = xs[ar][q ^ (ar & 7)];
    uint4 bv = ps[br][q ^ (br & 7)];
    s16x8 af, bf;
    __builtin_memcpy(&af, &av, 16);
    __builtin_memcpy(&bf, &bv, 16);
    acc = __builtin_amdgcn_mfma_f32_16x16x32_bf16(af, bf, acc, 0, 0, 0);
  }

  // ---- AEG fp32 tail on the accumulator tile ----
  // C/D layout (R3/R4-validated): col = lane&15, row = (lane>>4)*4 + reg
  const int lrow = wr * 16 + (lane >> 4) * 4;
  const int lcol = wc * 16 + (lane & 15);
  const int ocol = bn + lcol;

  float rr0 = 0.f, rr1 = 0.f, rr2 = 0.f, rr3 = 0.f;
  const bool ev = ((lcol & 1) == 0);      // parity of i (bn is even)

#define AEG4(WK, KEV, XQ0, XQ1, XQ2, XQ3)                                   \
  { const float wk = (WK);                                                  \
    { const float xv = (XQ0), p = wk * xv;                                  \
      const float m = (KEV) ? (ev ? xv : wk) : (ev ? wk : xv);              \
      rr0 = fmaf(rr0, m, p); }                                              \
    { const float xv = (XQ1), p = wk * xv;                                  \
      const float m = (KEV) ? (ev ? xv : wk) : (ev ? wk : xv);              \
      rr1 = fmaf(rr1, m, p); }                                              \
    { const float xv = (XQ2), p = wk * xv;                                  \
      const float m = (KEV) ? (ev ? xv : wk) : (ev ? wk : xv);              \
      rr2 = fmaf(rr2, m, p); }                                              \
    { const float xv = (XQ3), p = wk * xv;                                  \
      const float m = (KEV) ? (ev ? xv : wk) : (ev ? wk : xv);              \
      rr3 = fmaf(rr3, m, p); } }

  #pragma unroll
  for (int k4 = 0; k4 < KT; k4 += 4) {
    float4 wq  = *(const float4*)&wt[lcol][k4];
    float4 xq0 = *(const float4*)&xt[lrow + 0][k4];
    float4 xq1 = *(const float4*)&xt[lrow + 1][k4];
    float4 xq2 = *(const float4*)&xt[lrow + 2][k4];
    float4 xq3 = *(const float4*)&xt[lrow + 3][k4];
    AEG4(wq.x, true,  xq0.x, xq1.x, xq2.x, xq3.x);   // K0+k4   even
    AEG4(wq.y, false, xq0.y, xq1.y, xq2.y, xq3.y);   // K0+k4+1 odd
    AEG4(wq.z, true,  xq0.z, xq1.z, xq2.z, xq3.z);
    AEG4(wq.w, false, xq0.w, xq1.w, xq2.w, xq3.w);
  }
#undef AEG4

  // ---- epilogue: sigmoid(aeg) * (proj + bias) ----
  const float pbv = pb[ocol];
  out[(size_t)(bm + lrow + 0) * OUTF + ocol] = (acc[0] + pbv) / (1.f + __expf(-rr0));
  out[(size_t)(bm + lrow + 1) * OUTF + ocol] = (acc[1] + pbv) / (1.f + __expf(-rr1));
  out[(size_t)(bm + lrow + 2) * OUTF + ocol] = (acc[2] + pbv) / (1.f + __expf(-rr2));
  out[(size_t)(bm + lrow + 3) * OUTF + ocol] = (acc[3] + pbv) / (1.f + __expf(-rr3));
}

extern "C" void kernel_launch(void* const* d_in, const int* in_sizes, int n_in,
                              void* d_out, int out_size, void* d_ws, size_t ws_size,
                              hipStream_t stream) {
  const float* x  = (const float*)d_in[0];
  const float* w  = (const float*)d_in[1];   // (1,512,512) flat
  const float* pw = (const float*)d_in[2];
  const float* pb = (const float*)d_in[3];
  float* out = (float*)d_out;

  dim3 grid(OUTF / BN, BATCH / BM);          // (8,32) = 256 blocks = 1/CU
  semilinear_fused<<<grid, dim3(512), 0, stream>>>(x, w, pw, pb, out);
}